// Round 1
// baseline (8210.610 us; speedup 1.0000x reference)
//
#include <hip/hip_runtime.h>
#include <hip/hip_bf16.h>
#include <math.h>

#define NB 8
#define NS 1024
#define DM 1024
#define NH 16
#define NF 64

// ---------------------------------------------------------------------------
// K1: x[b,h,s,f] = sum_d sin[b,s,d] * Wx[h,d,f] + bx[h,f];  nrm[b,h,s] = ||x||
// One wave (64 lanes) per (b,h,s) row; lane = f.
// ---------------------------------------------------------------------------
__global__ __launch_bounds__(256) void proj_kernel(
    const float* __restrict__ sin_in, const float* __restrict__ Wx,
    const float* __restrict__ bx, float* __restrict__ x, float* __restrict__ nrm) {
  long gid = (long)blockIdx.x * 256 + threadIdx.x;   // over B*H*S*F
  int f = (int)(gid & 63);
  long row = gid >> 6;              // (b*NH + h)*NS + s
  int s = (int)(row & (NS - 1));
  long bh = row >> 10;              // b*NH + h
  int h = (int)(bh & (NH - 1));
  int b = (int)(bh >> 4);

  const float* sp = sin_in + ((long)(b * NS + s)) * DM;
  const float* wp = Wx + ((long)h * DM) * NF + f;
  float acc = bx[h * NF + f];
#pragma unroll 8
  for (int d = 0; d < DM; ++d) acc += sp[d] * wp[(long)d * NF];
  x[gid] = acc;

  // wave-wide sum of squares (64 lanes = the f dimension)
  float ss = acc * acc;
#pragma unroll
  for (int off = 32; off; off >>= 1) ss += __shfl_xor(ss, off, 64);
  if (f == 0) nrm[row] = sqrtf(ss);
}

// ---------------------------------------------------------------------------
// K2: per query row (b,h,s): scores over all t, softmax, PV.
// Block = 256 threads (4 waves). Scores staged in LDS.
// ---------------------------------------------------------------------------
__global__ __launch_bounds__(256) void attn_kernel(
    const float* __restrict__ x, const float* __restrict__ nrm,
    float* __restrict__ ao) {
  __shared__ float sc[NS];      // 4 KB
  __shared__ float xq[NF];
  __shared__ float rmax[4], rsum[4];
  __shared__ float pv[4][NF];

  int tid = threadIdx.x;
  int lane = tid & 63;
  int wv = tid >> 6;            // 0..3
  long row = blockIdx.x;        // (b*NH + h)*NS + s
  int s = (int)(row & (NS - 1));
  long bh = row >> 10;

  const float* xb = x + bh * (long)(NS * NF);
  const float* nb = nrm + bh * (long)NS;

  if (tid < NF) xq[tid] = xb[(long)s * NF + tid];
  __syncthreads();
  float qn = nb[s];

  // ---- scores: each thread computes 4 rows (t = tc*256 + tid) ----
  for (int tc = 0; tc < 4; ++tc) {
    int t = tc * 256 + tid;
    const float* xr = xb + (long)t * NF;
    float d = 0.f;
#pragma unroll 16
    for (int f = 0; f < NF; ++f) d += xq[f] * xr[f];
    float scv = d / (qn * nb[t]);
    if (scv == 0.0f) scv = -INFINITY;   // reference quirk
    sc[t] = scv;
  }
  __syncthreads();

  // ---- softmax over sc[0..1023] ----
  float m = -INFINITY;
  for (int t = tid; t < NS; t += 256) m = fmaxf(m, sc[t]);
#pragma unroll
  for (int off = 32; off; off >>= 1) m = fmaxf(m, __shfl_xor(m, off, 64));
  if (lane == 0) rmax[wv] = m;
  __syncthreads();
  m = fmaxf(fmaxf(rmax[0], rmax[1]), fmaxf(rmax[2], rmax[3]));

  float ssum = 0.f;
  for (int t = tid; t < NS; t += 256) {
    float e = __expf(sc[t] - m);
    sc[t] = e;
    ssum += e;
  }
#pragma unroll
  for (int off = 32; off; off >>= 1) ssum += __shfl_xor(ssum, off, 64);
  if (lane == 0) rsum[wv] = ssum;
  __syncthreads();
  float inv = 1.0f / (rsum[0] + rsum[1] + rsum[2] + rsum[3]);

  // ---- PV: lane = f, each wave accumulates its quarter of t ----
  float acc = 0.f;
  const float* xr = xb + (long)(wv * 256) * NF + lane;
  const float* scw = sc + wv * 256;
  for (int t = 0; t < 256; ++t) acc += scw[t] * xr[(long)t * NF];
  pv[wv][lane] = acc;
  __syncthreads();
  if (wv == 0) {
    float o = (pv[0][lane] + pv[1][lane] + pv[2][lane] + pv[3][lane]) * inv;
    int h = (int)(bh & (NH - 1));
    int b = (int)(bh >> 4);
    ao[((long)(b * NS + s)) * (NH * NF) + h * NF + lane] = o;
  }
}

// ---------------------------------------------------------------------------
// K3: out[r,c] = sum_d ao[r,d] * Wp[d,c] + bp[c]    (r over B*S, c over DM)
// ---------------------------------------------------------------------------
__global__ __launch_bounds__(256) void outproj_kernel(
    const float* __restrict__ ao, const float* __restrict__ Wp,
    const float* __restrict__ bp, float* __restrict__ out) {
  long gid = (long)blockIdx.x * 256 + threadIdx.x;   // over B*S*DM
  int c = (int)(gid & (DM - 1));
  long r = gid >> 10;                                // b*NS + s
  const float* ar = ao + r * (long)DM;
  float acc = bp[c];
#pragma unroll 8
  for (int d = 0; d < DM; ++d) acc += ar[d] * Wp[(long)d * DM + c];
  out[gid] = acc;
}

extern "C" void kernel_launch(void* const* d_in, const int* in_sizes, int n_in,
                              void* d_out, int out_size, void* d_ws, size_t ws_size,
                              hipStream_t stream) {
  const float* sin_in = (const float*)d_in[0];
  // d_in[1] = mask (unused; only its presence matters in the reference)
  const float* Wx = (const float*)d_in[2];
  const float* bx = (const float*)d_in[3];
  const float* Wp = (const float*)d_in[4];
  const float* bp = (const float*)d_in[5];
  float* out = (float*)d_out;

  float* x = (float*)d_ws;                                // B*H*S*F floats
  float* nrm = x + (size_t)NB * NH * NS * NF;             // B*H*S floats
  float* ao = nrm + (size_t)NB * NH * NS;                 // B*S*H*F floats

  {
    long total = (long)NB * NH * NS * NF;
    proj_kernel<<<(int)(total / 256), 256, 0, stream>>>(sin_in, Wx, bx, x, nrm);
  }
  {
    long rows = (long)NB * NH * NS;
    attn_kernel<<<(int)rows, 256, 0, stream>>>(x, nrm, ao);
  }
  {
    long total = (long)NB * NS * DM;
    outproj_kernel<<<(int)(total / 256), 256, 0, stream>>>(ao, Wp, bp, out);
  }
}

// Round 3
// 265.651 us; speedup vs baseline: 30.9075x; 30.9075x over previous
//
#include <hip/hip_runtime.h>
#include <hip/hip_bf16.h>
#include <math.h>

typedef _Float16 f16;
typedef _Float16 half8 __attribute__((ext_vector_type(8)));
typedef float f32x4 __attribute__((ext_vector_type(4)));

#define NB 8
#define NS 1024
#define DM 1024
#define NH 16
#define NF 64

// ---------------------------------------------------------------------------
// convert sin f32 -> f16 (8 elems/thread)
// ---------------------------------------------------------------------------
__global__ __launch_bounds__(256) void csin_kernel(const float* __restrict__ in, f16* __restrict__ out) {
  long gid = (long)blockIdx.x * 256 + threadIdx.x;
  const float4* p = (const float4*)(in + gid * 8);
  float4 a = p[0], b = p[1];
  half8 v;
  v[0] = (f16)a.x; v[1] = (f16)a.y; v[2] = (f16)a.z; v[3] = (f16)a.w;
  v[4] = (f16)b.x; v[5] = (f16)b.y; v[6] = (f16)b.z; v[7] = (f16)b.w;
  *(half8*)(out + gid * 8) = v;
}

// W2T[n][d] = Wx[n>>6][d][n&63]  (f16, n-major so GEMM B-frags read contiguous K)
__global__ __launch_bounds__(256) void cwx_kernel(const float* __restrict__ Wx, f16* __restrict__ W2T) {
  int gid = blockIdx.x * 256 + threadIdx.x;
  int n = gid >> 7;
  int d0 = (gid & 127) * 8;
  const float* src = Wx + (n >> 6) * (DM * NF) + (n & 63);
  half8 v;
#pragma unroll
  for (int j = 0; j < 8; ++j) v[j] = (f16)src[(size_t)(d0 + j) * NF];
  *(half8*)(W2T + (size_t)n * DM + d0) = v;
}

// WpT[n][d] = Wp[d][n]
__global__ __launch_bounds__(256) void cwp_kernel(const float* __restrict__ Wp, f16* __restrict__ WpT) {
  int gid = blockIdx.x * 256 + threadIdx.x;
  int n = gid >> 7;
  int d0 = (gid & 127) * 8;
  const float* src = Wp + n;
  half8 v;
#pragma unroll
  for (int j = 0; j < 8; ++j) v[j] = (f16)src[(size_t)(d0 + j) * DM];
  *(half8*)(WpT + (size_t)n * DM + d0) = v;
}

// ---------------------------------------------------------------------------
// GEMM: C[8192,1024] = A[8192,1024] @ Bt[n][k]^T + bias[n]
// MODE 0: write f16 to x in [b][h][s][f] layout.  MODE 1: write f32 row-major.
// 128x128 tile, BK=64, 4 waves (2x2), each wave 64x64 via 4x4 16x16 MFMA tiles.
// ---------------------------------------------------------------------------
template <int MODE>
__global__ __launch_bounds__(256) void gemm_kernel(const f16* __restrict__ A, const f16* __restrict__ Bt,
                                                   const float* __restrict__ bias, void* __restrict__ Cv) {
  __shared__ f16 As[128][72];  // pad to 72 f16 (144B, 16B-multiple) for aligned b128 + conflict relief
  __shared__ f16 Bs[128][72];
  int tid = threadIdx.x;
  int l = tid & 63, wv = tid >> 6;
  int wm = wv >> 1, wn = wv & 1;
  int bm = blockIdx.x >> 3, bn = blockIdx.x & 7;
  int lr = l & 15, lh = l >> 4;

  f32x4 acc[4][4];
#pragma unroll
  for (int i = 0; i < 4; ++i)
#pragma unroll
    for (int j = 0; j < 4; ++j) acc[i][j] = (f32x4)0.f;

  for (int k0 = 0; k0 < DM; k0 += 64) {
    __syncthreads();
#pragma unroll
    for (int c = 0; c < 4; ++c) {
      int idx = c * 256 + tid;
      int row = idx >> 3, ch = idx & 7;
      *(half8*)&As[row][ch * 8] = *(const half8*)(A + (size_t)(bm * 128 + row) * DM + k0 + ch * 8);
      *(half8*)&Bs[row][ch * 8] = *(const half8*)(Bt + (size_t)(bn * 128 + row) * DM + k0 + ch * 8);
    }
    __syncthreads();
#pragma unroll
    for (int ks = 0; ks < 2; ++ks) {
      half8 af[4], bf[4];
#pragma unroll
      for (int mi = 0; mi < 4; ++mi) af[mi] = *(const half8*)&As[wm * 64 + mi * 16 + lr][ks * 32 + lh * 8];
#pragma unroll
      for (int ni = 0; ni < 4; ++ni) bf[ni] = *(const half8*)&Bs[wn * 64 + ni * 16 + lr][ks * 32 + lh * 8];
#pragma unroll
      for (int mi = 0; mi < 4; ++mi)
#pragma unroll
        for (int ni = 0; ni < 4; ++ni)
          acc[mi][ni] = __builtin_amdgcn_mfma_f32_16x16x32_f16(af[mi], bf[ni], acc[mi][ni], 0, 0, 0);
    }
  }

#pragma unroll
  for (int mi = 0; mi < 4; ++mi)
#pragma unroll
    for (int ni = 0; ni < 4; ++ni) {
      int gc = bn * 128 + wn * 64 + ni * 16 + lr;
      float bv = bias[gc];
#pragma unroll
      for (int r = 0; r < 4; ++r) {
        int gr = bm * 128 + wm * 64 + mi * 16 + lh * 4 + r;
        float v = acc[mi][ni][r] + bv;
        if (MODE == 0) {
          f16* x = (f16*)Cv;
          int b = gr >> 10, s = gr & 1023, h = gc >> 6, f = gc & 63;
          x[(size_t)((b * NH + h) * NS + s) * NF + f] = (f16)v;
        } else {
          ((float*)Cv)[(size_t)gr * DM + gc] = v;
        }
      }
    }
}

// ---------------------------------------------------------------------------
// invn[row] = 1/||x_row||  (4 lanes per 64-f16 row)
// ---------------------------------------------------------------------------
__global__ __launch_bounds__(256) void norm_kernel(const f16* __restrict__ x, float* __restrict__ invn) {
  int gid = blockIdx.x * 256 + threadIdx.x;
  int row = gid >> 2, sub = gid & 3;
  const f16* p = x + (size_t)row * NF + sub * 16;
  half8 a = *(const half8*)p;
  half8 b = *(const half8*)(p + 8);
  float ss = 0.f;
#pragma unroll
  for (int i = 0; i < 8; ++i) {
    float u = (float)a[i], w = (float)b[i];
    ss += u * u + w * w;
  }
  ss += __shfl_xor(ss, 1, 64);
  ss += __shfl_xor(ss, 2, 64);
  if (sub == 0) invn[row] = 1.0f / sqrtf(ss);
}

// ---------------------------------------------------------------------------
// Attention: per block = (bh, q-tile of 128). Cosine scores are in [-1,1]
// (Cauchy-Schwarz) => fixed softmax max of 1: p = exp(s-1), single pass,
// accumulate PV + rowsum. Quirk: s==0 -> p=0 (matches ref's -inf).
// ---------------------------------------------------------------------------
__global__ __launch_bounds__(256) void attn_kernel(const f16* __restrict__ x, const float* __restrict__ invn,
                                                   f16* __restrict__ ao) {
  __shared__ f16 Xk[128][72];    // [t][f]
  __shared__ f16 XkT[64][136];   // [f][t]  (for PV B-operand: K=t contiguous)
  __shared__ f16 P[128][136];    // [q][t]  (per-wave 32-row region)
  __shared__ float sn[NS];

  int tid = threadIdx.x;
  int l = tid & 63, wv = tid >> 6;
  int lr = l & 15, lh = l >> 4;
  int bh = blockIdx.x >> 3, q0 = (blockIdx.x & 7) * 128;
  const f16* xb = x + (size_t)bh * (NS * NF);

  for (int i = tid; i < NS; i += 256) sn[i] = invn[bh * NS + i];

  int wq = wv * 32;  // wave's q offset inside the 128-row tile
  half8 aq[2][2];    // Q fragments, resident for the whole block
#pragma unroll
  for (int mi = 0; mi < 2; ++mi)
#pragma unroll
    for (int ks = 0; ks < 2; ++ks)
      aq[mi][ks] = *(const half8*)(xb + (size_t)(q0 + wq + mi * 16 + lr) * NF + ks * 32 + lh * 8);

  __syncthreads();
  float qn_[2][4];
#pragma unroll
  for (int mi = 0; mi < 2; ++mi)
#pragma unroll
    for (int r = 0; r < 4; ++r) qn_[mi][r] = sn[q0 + wq + mi * 16 + lh * 4 + r];

  f32x4 accO[2][4];
  float rs[2][4];
#pragma unroll
  for (int mi = 0; mi < 2; ++mi) {
#pragma unroll
    for (int ni = 0; ni < 4; ++ni) accO[mi][ni] = (f32x4)0.f;
#pragma unroll
    for (int r = 0; r < 4; ++r) rs[mi][r] = 0.f;
  }

  for (int t0 = 0; t0 < NS; t0 += 128) {
    __syncthreads();  // previous iteration's Xk/XkT reads complete
#pragma unroll
    for (int c = 0; c < 4; ++c) {
      int idx = c * 256 + tid;
      int tr = idx >> 3, fo = (idx & 7) * 8;
      half8 v = *(const half8*)(xb + (size_t)(t0 + tr) * NF + fo);
      *(half8*)&Xk[tr][fo] = v;
#pragma unroll
      for (int j = 0; j < 8; ++j) XkT[fo + j][tr] = v[j];
    }
    __syncthreads();

    // ---- QK^T: S[q][t], wave covers q in [wq,wq+32), all 128 t ----
    f32x4 s[2][8];
#pragma unroll
    for (int mi = 0; mi < 2; ++mi)
#pragma unroll
      for (int ni = 0; ni < 8; ++ni) s[mi][ni] = (f32x4)0.f;
#pragma unroll
    for (int ks = 0; ks < 2; ++ks) {
      half8 bk[8];
#pragma unroll
      for (int ni = 0; ni < 8; ++ni) bk[ni] = *(const half8*)&Xk[ni * 16 + lr][ks * 32 + lh * 8];
#pragma unroll
      for (int mi = 0; mi < 2; ++mi)
#pragma unroll
        for (int ni = 0; ni < 8; ++ni)
          s[mi][ni] = __builtin_amdgcn_mfma_f32_16x16x32_f16(aq[mi][ks], bk[ni], s[mi][ni], 0, 0, 0);
    }

    // ---- scale to cosine, exp(s-1), rowsum, P -> LDS (f16) ----
#pragma unroll
    for (int ni = 0; ni < 8; ++ni) {
      float kn = sn[t0 + ni * 16 + lr];
#pragma unroll
      for (int mi = 0; mi < 2; ++mi)
#pragma unroll
        for (int r = 0; r < 4; ++r) {
          float sv = s[mi][ni][r] * qn_[mi][r] * kn;
          float e = (sv == 0.f) ? 0.f : __expf(sv - 1.f);
          rs[mi][r] += e;
          P[wq + mi * 16 + lh * 4 + r][ni * 16 + lr] = (f16)e;
        }
    }

    // ---- PV: O[q][f] += P[q][t] @ Xk[t][f] ----
#pragma unroll
    for (int ks = 0; ks < 4; ++ks) {
      half8 pa[2], vb[4];
#pragma unroll
      for (int mi = 0; mi < 2; ++mi) pa[mi] = *(const half8*)&P[wq + mi * 16 + lr][ks * 32 + lh * 8];
#pragma unroll
      for (int ni = 0; ni < 4; ++ni) vb[ni] = *(const half8*)&XkT[ni * 16 + lr][ks * 32 + lh * 8];
#pragma unroll
      for (int mi = 0; mi < 2; ++mi)
#pragma unroll
        for (int ni = 0; ni < 4; ++ni)
          accO[mi][ni] = __builtin_amdgcn_mfma_f32_16x16x32_f16(pa[mi], vb[ni], accO[mi][ni], 0, 0, 0);
    }
  }

  // rowsum: reduce across the 16 lanes sharing each q row
#pragma unroll
  for (int mi = 0; mi < 2; ++mi)
#pragma unroll
    for (int r = 0; r < 4; ++r) {
      float v = rs[mi][r];
      v += __shfl_xor(v, 1, 64);
      v += __shfl_xor(v, 2, 64);
      v += __shfl_xor(v, 4, 64);
      v += __shfl_xor(v, 8, 64);
      rs[mi][r] = v;
    }

  int b = bh >> 4, h = bh & 15;
#pragma unroll
  for (int mi = 0; mi < 2; ++mi)
#pragma unroll
    for (int ni = 0; ni < 4; ++ni)
#pragma unroll
      for (int r = 0; r < 4; ++r) {
        int s_g = q0 + wq + mi * 16 + lh * 4 + r;
        int f = ni * 16 + lr;
        float v = accO[mi][ni][r] / rs[mi][r];
        ao[(size_t)(b * NS + s_g) * DM + h * NF + f] = (f16)v;  // concat-head layout [bs][h*64+f]
      }
}

extern "C" void kernel_launch(void* const* d_in, const int* in_sizes, int n_in,
                              void* d_out, int out_size, void* d_ws, size_t ws_size,
                              hipStream_t stream) {
  const float* sin_in = (const float*)d_in[0];
  // d_in[1] = mask (presence-only in reference)
  const float* Wx = (const float*)d_in[2];
  const float* bx = (const float*)d_in[3];
  const float* Wp = (const float*)d_in[4];
  const float* bp = (const float*)d_in[5];
  float* out = (float*)d_out;

  char* p = (char*)d_ws;
  f16* sinb = (f16*)p;                      p += (size_t)NB * NS * DM * 2;   // 16.78 MB
  f16* x    = (f16*)p;                      p += (size_t)NB * NH * NS * NF * 2;
  f16* ao   = (f16*)p;                      p += (size_t)NB * NS * DM * 2;
  f16* W2T  = (f16*)p;                      p += (size_t)DM * DM * 2;
  f16* WpT  = (f16*)p;                      p += (size_t)DM * DM * 2;
  float* invn = (float*)p;

  csin_kernel<<<4096, 256, 0, stream>>>(sin_in, sinb);
  cwx_kernel<<<512, 256, 0, stream>>>(Wx, W2T);
  cwp_kernel<<<512, 256, 0, stream>>>(Wp, WpT);
  gemm_kernel<0><<<512, 256, 0, stream>>>(sinb, W2T, bx, (void*)x);
  norm_kernel<<<2048, 256, 0, stream>>>(x, invn);
  attn_kernel<<<1024, 256, 0, stream>>>(x, invn, ao);
  gemm_kernel<1><<<512, 256, 0, stream>>>(ao, WpT, bp, (void*)out);
}